// Round 1
// baseline (651.781 us; speedup 1.0000x reference)
//
#include <hip/hip_runtime.h>
#include <stdint.h>

// Sizes (fixed by the problem)
#define N_PATCH 8192
#define DIM     1024
#define HID     512
#define NHEAD   16

using short8 = __attribute__((ext_vector_type(8))) short;
using f32x4  = __attribute__((ext_vector_type(4))) float;

__device__ __forceinline__ unsigned short f2bf(float f) {
  unsigned u = __float_as_uint(f);
  u = u + 0x7fffu + ((u >> 16) & 1u);   // round-to-nearest-even
  return (unsigned short)(u >> 16);
}

// global -> LDS direct copy, 16B per lane (CK addrspace-cast pattern)
__device__ __forceinline__ void gload_lds16(const void* g, void* l) {
  __builtin_amdgcn_global_load_lds(
      reinterpret_cast<const __attribute__((address_space(1))) void*>(
          reinterpret_cast<uintptr_t>(g)),
      reinterpret_cast<__attribute__((address_space(3))) void*>(
          reinterpret_cast<uintptr_t>(l)),
      16, 0, 0);
}

// ---------------- x fp32 -> bf16 ----------------
__global__ void convert_x_kernel(const float* __restrict__ x,
                                 unsigned short* __restrict__ xb) {
  const int total4 = (N_PATCH * DIM) / 4;  // 2,097,152
  for (int i = blockIdx.x * blockDim.x + threadIdx.x; i < total4;
       i += gridDim.x * blockDim.x) {
    float4 v = ((const float4*)x)[i];
    ushort4 o;
    o.x = f2bf(v.x); o.y = f2bf(v.y); o.z = f2bf(v.z); o.w = f2bf(v.w);
    ((ushort4*)xb)[i] = o;
  }
}

// ---------------- pack Vw/Uw -> Wpt[k][c][d] bf16 (transposed, V/U interleaved per 16 cols) ----
// c = (h>>4)*32 + u*16 + (h&15),  u=0:V  u=1:U
__global__ void pack_w_kernel(const float* __restrict__ Vw,
                              const float* __restrict__ Uw,
                              unsigned short* __restrict__ Wpt) {
  __shared__ unsigned short T[128][68];   // +4 pad vs 64 to spread banks
  const int hc = blockIdx.x;   // 0..7   (h chunk of 64)
  const int dc = blockIdx.y;   // 0..15  (d chunk of 64)
  const int k  = blockIdx.z;   // head
  const int t  = threadIdx.x;  // 256
  const int d0 = dc * 64, h0 = hc * 64;
  const size_t base = (size_t)k * DIM * HID;
  for (int u = 0; u < 2; ++u) {
    const float* W = u ? Uw : Vw;
    #pragma unroll
    for (int i = 0; i < 16; ++i) {
      int idx = i * 256 + t;
      int dd = idx >> 6, hh = idx & 63;
      float v = W[base + (size_t)(d0 + dd) * HID + h0 + hh];
      int cl = ((hh >> 4) << 5) + (u << 4) + (hh & 15);
      T[cl][dd] = f2bf(v);
    }
  }
  __syncthreads();
  const size_t obase = ((size_t)k * 1024 + hc * 128) * DIM + d0;
  #pragma unroll
  for (int i = 0; i < 8; ++i) {
    int idx = i * 1024 + t * 4;       // elem in 128x64 tile
    int cl = idx >> 6, dd = idx & 63;
    ushort4 o;
    o.x = T[cl][dd]; o.y = T[cl][dd + 1]; o.z = T[cl][dd + 2]; o.w = T[cl][dd + 3];
    *(ushort4*)&Wpt[obase + (size_t)cl * DIM + dd] = o;
  }
}

// ---------------- main GEMM + gated epilogue -> score partials ----------------
// grid: (ct=8, mt=64, head=16). 128x128 tile, BK=64, 4 waves (2x2), dbuf LDS.
__global__ __launch_bounds__(256, 2) void gemm_scores_kernel(
    const unsigned short* __restrict__ xb,
    const unsigned short* __restrict__ Wpt,
    const float* __restrict__ Vb, const float* __restrict__ Ub,
    const float* __restrict__ ww, float* __restrict__ part) {
  __shared__ unsigned short As[2][128 * 64];
  __shared__ unsigned short Bs[2][128 * 64];
  const int ct = blockIdx.x;
  const int mt = blockIdx.y;
  const int kh = blockIdx.z;
  const int tid = threadIdx.x;
  const int wv = tid >> 6, lane = tid & 63;
  const int wr = wv >> 1, wc = wv & 1;

  const unsigned short* Abase = xb + (size_t)mt * 128 * DIM;
  const unsigned short* Bbase = Wpt + ((size_t)kh * 1024 + ct * 128) * DIM;

  const f32x4 vzero = {0.f, 0.f, 0.f, 0.f};
  f32x4 acc[4][4];
  #pragma unroll
  for (int i = 0; i < 4; ++i)
    #pragma unroll
    for (int j = 0; j < 4; ++j) acc[i][j] = vzero;

  auto stage = [&](int buf, int kt) {
    const int dbase = kt * 64;
    #pragma unroll
    for (int i = 0; i < 4; ++i) {
      const int flat = i * 4096 + tid * 16;  // byte offset in 16KB tile
      const int r = flat >> 7;               // 128B per row (64 bf16)
      const int cb = flat & 127;
      const int ldst = (i * 4096 + wv * 1024) >> 1;  // wave-uniform LDS base (ushorts)
      gload_lds16(Abase + (size_t)r * DIM + dbase + (cb >> 1), &As[buf][ldst]);
      gload_lds16(Bbase + (size_t)r * DIM + dbase + (cb >> 1), &Bs[buf][ldst]);
    }
  };

  auto compute = [&](int buf) {
    #pragma unroll
    for (int ks = 0; ks < 2; ++ks) {
      const int kb = ks * 32 + (lane >> 4) * 8;
      short8 a[4], b[4];
      #pragma unroll
      for (int i = 0; i < 4; ++i) {
        a[i] = *(const short8*)&As[buf][(wr * 64 + i * 16 + (lane & 15)) * 64 + kb];
        b[i] = *(const short8*)&Bs[buf][(wc * 64 + i * 16 + (lane & 15)) * 64 + kb];
      }
      #pragma unroll
      for (int i = 0; i < 4; ++i)
        #pragma unroll
        for (int j = 0; j < 4; ++j)
          acc[i][j] = __builtin_amdgcn_mfma_f32_16x16x32_bf16(a[i], b[j], acc[i][j], 0, 0, 0);
    }
  };

  stage(0, 0);
  __syncthreads();
  #pragma unroll 2
  for (int kt = 0; kt < 16; ++kt) {
    const int cur = kt & 1;
    if (kt < 15) stage(cur ^ 1, kt + 1);
    compute(cur);
    __syncthreads();
  }

  // epilogue: tanh(AV+Vb)*sigmoid(AU+Ub)*ww, reduce over the 128 cols this block owns
  float partial[4][4];
  #pragma unroll
  for (int i = 0; i < 4; ++i)
    #pragma unroll
    for (int r = 0; r < 4; ++r) partial[i][r] = 0.f;

  #pragma unroll
  for (int p = 0; p < 2; ++p) {
    const int h = (ct * 4 + wc * 2 + p) * 16 + (lane & 15);
    const float vb = Vb[kh * HID + h];
    const float ub = Ub[kh * HID + h];
    const float wwv = ww[kh * HID + h];
    #pragma unroll
    for (int mi = 0; mi < 4; ++mi)
      #pragma unroll
      for (int r = 0; r < 4; ++r) {
        const float av = tanhf(acc[mi][2 * p][r] + vb);
        const float xu = acc[mi][2 * p + 1][r] + ub;
        const float au = 1.f / (1.f + __expf(-xu));
        partial[mi][r] += av * au * wwv;
      }
  }
  #pragma unroll
  for (int s = 1; s < 16; s <<= 1)
    #pragma unroll
    for (int mi = 0; mi < 4; ++mi)
      #pragma unroll
      for (int r = 0; r < 4; ++r)
        partial[mi][r] += __shfl_xor(partial[mi][r], s, 64);

  if ((lane & 15) == 0) {
    const int j = ct * 2 + wc;  // 0..15 partial slot
    float* dst = part + ((size_t)j * NHEAD + kh) * N_PATCH;
    const int rbase = mt * 128 + wr * 64 + (lane >> 4) * 4;
    #pragma unroll
    for (int mi = 0; mi < 4; ++mi)
      #pragma unroll
      for (int r = 0; r < 4; ++r)
        dst[rbase + mi * 16 + r] = partial[mi][r];
  }
}

// ---------------- scores = sum of 16 partials ----------------
__global__ void reduce_scores_kernel(const float* __restrict__ part,
                                     float* __restrict__ scores) {
  int idx = blockIdx.x * 256 + threadIdx.x;  // 131072 = 16*8192
  int k = idx >> 13, n = idx & 8191;
  float s = 0.f;
  #pragma unroll
  for (int j = 0; j < 16; ++j) s += part[((size_t)j * NHEAD + k) * N_PATCH + n];
  scores[idx] = s;
}

// ---------------- per-head softmax stats (max, sumexp) ----------------
__global__ void softmax_stats_kernel(const float* __restrict__ scores,
                                     float* __restrict__ stats) {
  const int k = blockIdx.x;
  const float* s = scores + (size_t)k * N_PATCH;
  __shared__ float shm[4], shs[4];
  float v[32];
  float mx = -1e30f;
  #pragma unroll
  for (int i = 0; i < 32; ++i) {
    v[i] = s[i * 256 + threadIdx.x];
    mx = fmaxf(mx, v[i]);
  }
  #pragma unroll
  for (int sft = 32; sft; sft >>= 1) mx = fmaxf(mx, __shfl_xor(mx, sft, 64));
  const int wv = threadIdx.x >> 6;
  if ((threadIdx.x & 63) == 0) shm[wv] = mx;
  __syncthreads();
  mx = fmaxf(fmaxf(shm[0], shm[1]), fmaxf(shm[2], shm[3]));
  float sum = 0.f;
  #pragma unroll
  for (int i = 0; i < 32; ++i) sum += __expf(v[i] - mx);
  #pragma unroll
  for (int sft = 32; sft; sft >>= 1) sum += __shfl_xor(sum, sft, 64);
  if ((threadIdx.x & 63) == 0) shs[wv] = sum;
  __syncthreads();
  if (threadIdx.x == 0) {
    stats[2 * k] = mx;
    stats[2 * k + 1] = shs[0] + shs[1] + shs[2] + shs[3];
  }
}

// ---------------- w[n] = sum_k softmax_k(n) ----------------
__global__ void compute_w_kernel(const float* __restrict__ scores,
                                 const float* __restrict__ stats,
                                 float* __restrict__ w) {
  int n = blockIdx.x * 256 + threadIdx.x;
  float acc = 0.f;
  #pragma unroll
  for (int k = 0; k < NHEAD; ++k) {
    float rl = 1.f / stats[2 * k + 1];
    acc += __expf(scores[(size_t)k * N_PATCH + n] - stats[2 * k]) * rl;
  }
  w[n] = acc;
}

// ---------------- y1[d]=sum w[n]x[n,d], y2[d]=sum x[n,d]  (partials) ----------------
__global__ void weighted_part_kernel(const float* __restrict__ x,
                                     const float* __restrict__ w,
                                     float* __restrict__ wp1,
                                     float* __restrict__ wp2) {
  const int d = blockIdx.x * 256 + threadIdx.x;  // grid.x = 4
  const int nc = blockIdx.y;                     // 32 chunks of 256 rows
  float a1 = 0.f, a2 = 0.f;
  for (int i = 0; i < 256; ++i) {
    int n = nc * 256 + i;
    float xv = x[(size_t)n * DIM + d];
    a1 += w[n] * xv;
    a2 += xv;
  }
  wp1[nc * DIM + d] = a1;
  wp2[nc * DIM + d] = a2;
}

__global__ void reduce_vec_kernel(const float* __restrict__ wp1,
                                  const float* __restrict__ wp2,
                                  float* __restrict__ y1,
                                  float* __restrict__ mvec) {
  int d = blockIdx.x * 256 + threadIdx.x;
  float s1 = 0.f, s2 = 0.f;
  #pragma unroll
  for (int i = 0; i < 32; ++i) {
    s1 += wp1[i * DIM + d];
    s2 += wp2[i * DIM + d];
  }
  y1[d] = s1;
  mvec[d] = s2 * (1.f / (float)N_PATCH);
}

// ---------------- split-K GEMV partial: part[kc][j] = sum_{d in chunk} in[d]*W[d,j] ----------
__global__ void gemv_part_kernel(const float* __restrict__ in,
                                 const float* __restrict__ W,
                                 float* __restrict__ part, int In, int Out) {
  int j = blockIdx.x * blockDim.x + threadIdx.x;
  int kc = blockIdx.y;
  int chunk = In / gridDim.y;
  if (j >= Out) return;
  const float* Wp = W + (size_t)(kc * chunk) * Out + j;
  float acc = 0.f;
  for (int d = 0; d < chunk; ++d) acc += in[kc * chunk + d] * Wp[(size_t)d * Out];
  part[kc * Out + j] = acc;
}

__global__ void gemv_combine_kernel(const float* __restrict__ part, int nkc,
                                    const float* __restrict__ bias,
                                    const float* __restrict__ extra, float scale,
                                    int do_relu, float* __restrict__ out, int Out) {
  int j = blockIdx.x * blockDim.x + threadIdx.x;
  if (j >= Out) return;
  float v = bias[j];
  for (int kc = 0; kc < nkc; ++kc) v += part[kc * Out + j];
  if (extra) v += extra[j];
  v *= scale;
  if (do_relu) v = fmaxf(v, 0.f);
  out[j] = v;
}

// ---------------- final: logits = c3 @ cW4 + cb4 ; softmax -> out ----------------
__global__ void final_head_kernel(const float* __restrict__ c3,
                                  const float* __restrict__ W,
                                  const float* __restrict__ b,
                                  float* __restrict__ out) {
  __shared__ float logits[9];
  int t = threadIdx.x;
  if (t < 9) {
    float acc = b[t];
    for (int d = 0; d < 256; ++d) acc += c3[d] * W[d * 9 + t];
    logits[t] = acc;
  }
  __syncthreads();
  if (t == 0) {
    float mx = logits[0];
    for (int j = 1; j < 9; ++j) mx = fmaxf(mx, logits[j]);
    float e[9], s = 0.f;
    for (int j = 0; j < 9; ++j) { e[j] = expf(logits[j] - mx); s += e[j]; }
    for (int j = 0; j < 9; ++j) out[j] = e[j] / s;
  }
}

extern "C" void kernel_launch(void* const* d_in, const int* in_sizes, int n_in,
                              void* d_out, int out_size, void* d_ws, size_t ws_size,
                              hipStream_t stream) {
  (void)in_sizes; (void)n_in; (void)out_size; (void)ws_size;
  const float* x   = (const float*)d_in[0];
  const float* Vw  = (const float*)d_in[1];
  const float* Vb  = (const float*)d_in[2];
  const float* Uw  = (const float*)d_in[3];
  const float* Ub  = (const float*)d_in[4];
  const float* ww  = (const float*)d_in[5];
  // d_in[6] = wb: constant shift per head -> softmax invariant -> unused
  const float* pW1 = (const float*)d_in[7];
  const float* pb1 = (const float*)d_in[8];
  const float* pW2 = (const float*)d_in[9];
  const float* pb2 = (const float*)d_in[10];
  const float* cW1 = (const float*)d_in[11];
  const float* cb1 = (const float*)d_in[12];
  const float* cW2 = (const float*)d_in[13];
  const float* cb2 = (const float*)d_in[14];
  const float* cW3 = (const float*)d_in[15];
  const float* cb3 = (const float*)d_in[16];
  const float* cW4 = (const float*)d_in[17];
  const float* cb4 = (const float*)d_in[18];
  float* out = (float*)d_out;

  char* ws = (char*)d_ws;
  size_t o = 0;
  auto alloc = [&](size_t bytes) -> char* {
    char* p = ws + o;
    o += (bytes + 255) & ~(size_t)255;
    return p;
  };
  unsigned short* xb  = (unsigned short*)alloc((size_t)N_PATCH * DIM * 2);      // 16 MB
  unsigned short* Wpt = (unsigned short*)alloc((size_t)NHEAD * 1024 * DIM * 2); // 32 MB
  float* part   = (float*)alloc((size_t)16 * NHEAD * N_PATCH * 4);              // 8 MB
  float* scores = (float*)alloc((size_t)NHEAD * N_PATCH * 4);
  float* stats  = (float*)alloc(NHEAD * 2 * 4);
  float* wvec   = (float*)alloc(N_PATCH * 4);
  float* wp1    = (float*)alloc(32 * DIM * 4);
  float* wp2    = (float*)alloc(32 * DIM * 4);
  float* y1     = (float*)alloc(DIM * 4);
  float* mvec   = (float*)alloc(DIM * 4);
  float* h1part = (float*)alloc(8 * HID * 4);
  float* h1     = (float*)alloc(HID * 4);
  float* agpart = (float*)alloc(4 * DIM * 4);
  float* aggr   = (float*)alloc(DIM * 4);
  float* c1part = (float*)alloc(8 * 1024 * 4);
  float* c1     = (float*)alloc(1024 * 4);
  float* c2part = (float*)alloc(8 * 512 * 4);
  float* c2     = (float*)alloc(512 * 4);
  float* c3part = (float*)alloc(4 * 256 * 4);
  float* c3     = (float*)alloc(256 * 4);

  convert_x_kernel<<<2048, 256, 0, stream>>>(x, xb);
  pack_w_kernel<<<dim3(8, 16, 16), 256, 0, stream>>>(Vw, Uw, Wpt);
  gemm_scores_kernel<<<dim3(8, 64, 16), 256, 0, stream>>>(xb, Wpt, Vb, Ub, ww, part);
  reduce_scores_kernel<<<512, 256, 0, stream>>>(part, scores);
  softmax_stats_kernel<<<16, 256, 0, stream>>>(scores, stats);
  compute_w_kernel<<<32, 256, 0, stream>>>(scores, stats, wvec);
  weighted_part_kernel<<<dim3(4, 32), 256, 0, stream>>>(x, wvec, wp1, wp2);
  reduce_vec_kernel<<<4, 256, 0, stream>>>(wp1, wp2, y1, mvec);
  gemv_part_kernel<<<dim3(2, 8), 256, 0, stream>>>(mvec, pW1, h1part, DIM, HID);
  gemv_combine_kernel<<<2, 256, 0, stream>>>(h1part, 8, pb1, nullptr, 1.f, 1, h1, HID);
  gemv_part_kernel<<<dim3(4, 4), 256, 0, stream>>>(h1, pW2, agpart, HID, DIM);
  gemv_combine_kernel<<<4, 256, 0, stream>>>(agpart, 4, pb2, y1, 1.f / 17.f, 0, aggr, DIM);
  gemv_part_kernel<<<dim3(4, 8), 256, 0, stream>>>(aggr, cW1, c1part, 1024, 1024);
  gemv_combine_kernel<<<4, 256, 0, stream>>>(c1part, 8, cb1, nullptr, 1.f, 1, c1, 1024);
  gemv_part_kernel<<<dim3(2, 8), 256, 0, stream>>>(c1, cW2, c2part, 1024, 512);
  gemv_combine_kernel<<<2, 256, 0, stream>>>(c2part, 8, cb2, nullptr, 1.f, 1, c2, 512);
  gemv_part_kernel<<<dim3(1, 4), 256, 0, stream>>>(c2, cW3, c3part, 512, 256);
  gemv_combine_kernel<<<1, 256, 0, stream>>>(c3part, 4, cb3, nullptr, 1.f, 1, c3, 256);
  final_head_kernel<<<1, 64, 0, stream>>>(c3, cW4, cb4, out);
}